// Round 5
// baseline (856909.082 us; speedup 1.0000x reference)
//
#include <hip/hip_runtime.h>
#include <hip/hip_cooperative_groups.h>
#include <math.h>

namespace cg = cooperative_groups;

#define NA      1500
#define NEDGE   48000
#define NDIM    4500
#define NB      9
#define TLD     1152
#define ZCHW    576
#define YLD     1152
#define CAPSM   640
#define CAP8    1152
#define SWEEPSB 10
#define NSWLOC  8
#define TSLOTS  196
#define SORTN   8192
#define COEFLD  864
#define NOUT    4494
#define PA      20          /* atoms per cheb tile */
#define NAG     75          /* 1500/PA */
#define CBGRID  256         /* coop cheb grid: <=256 so 1 block/CU co-residency always suffices */
#define PI_D    3.14159265358979323846

static const int H_DEG[NB] = {32, 80, 160, 256, 512, 512, 544, 544, 448};
__device__ __constant__ int d_DEG[NB] = {32, 80, 160, 256, 512, 512, 544, 544, 448};
__device__ __constant__ double d_MASS[10] = {1.008,4.003,6.941,9.012,10.811,12.011,14.007,15.999,18.998,20.18};
// Voronoi band intervals in eigenvalue space (band 8 = merged z=8,9)
__device__ __constant__ double d_BLO[NB] = {31.04695, 9.84715, 6.37590, 5.08655, 4.39385, 3.86620, 3.34740, 2.87855, -1.0e9};
__device__ __constant__ double d_BHI[NB] = {1.0e9, 31.04695, 9.84715, 6.37590, 5.08655, 4.39385, 3.86620, 3.34740, 2.87855};

// ---------------- workspace layout (bytes) ----------------
constexpr size_t O_DESC = 0;
constexpr size_t O_WM   = 32768;                         // f64[1536]  1/sqrt(m) per atom
constexpr size_t O_MINV = O_WM + 12288;                  // f64[1536]  1/m per atom
constexpr size_t O_GER  = O_MINV + 12288;                // f64[2*1500] gersh hi/lo per atom
constexpr size_t O_CH   = O_GER + 24576;                 // f64: c, h
constexpr size_t O_COEF = O_CH + 256;                    // f64[9*864]
constexpr size_t O_DT   = O_COEF + (size_t)NB*COEFLD*8;  // f64[4500*9]
constexpr size_t O_PD   = O_DT + (size_t)NDIM*9*8;       // f64[9*1152*9]
constexpr size_t O_RB   = O_PD + (size_t)NB*1152*9*8;    // f64[9*1152*9]
constexpr size_t O_EVA  = O_RB + (size_t)NB*1152*9*8;    // f64[8192]
constexpr size_t O_SID  = O_EVA + (size_t)SORTN*8;       // int[8192]
constexpr size_t O_HCOL = O_SID + (size_t)SORTN*4;       // int[1500*65]
constexpr size_t O_HV64 = O_HCOL + (size_t)NA*65*4;      // f64[1500*65*9]
constexpr size_t O_HV32 = O_HV64 + (size_t)NA*65*9*8;    // f32[1500*65*12] (12-padded rows)
constexpr size_t O_Y    = O_HV32 + (size_t)NA*65*12*4;   // f32[4500*1152]
constexpr size_t O_X1   = O_Y + (size_t)NDIM*YLD*4;      // f64[4500*1152]; aliases TP/TC f32 bufs
constexpr size_t O_X2   = O_X1 + (size_t)NDIM*YLD*8;     // f64[4500*1152]
constexpr size_t O_S    = O_X2 + (size_t)NDIM*YLD*8;     // f64[1152^2]; Z chunk aliases S..P
constexpr size_t O_P    = O_S + (size_t)CAP8*CAP8*8;     // f64[1152^2]
constexpr size_t O_G    = O_P + (size_t)CAP8*CAP8*8;     // f64[8*640^2 + 1152^2]
constexpr size_t GTOT   = (size_t)8*CAPSM*CAPSM + (size_t)CAP8*CAP8;
constexpr size_t O_J    = O_G + GTOT*8;
constexpr size_t WS_NEED = O_J + GTOT*8;                 // ~213 MB

__host__ __device__ inline size_t goffd(int g){ return (g < 8) ? (size_t)g*CAPSM*CAPSM : (size_t)8*CAPSM*CAPSM; }
__host__ inline int capb(int g){ return (g < 8) ? CAPSM : CAP8; }

// ---------------- prep ----------------
__global__ void k_prep(const int* __restrict__ z, char* ws) {
  int* desc = (int*)ws;
  double* wm = (double*)(ws + O_WM);
  double* minv = (double*)(ws + O_MINV);
  __shared__ int zb[NA];
  __shared__ int cnt[NB];
  int tid = threadIdx.x;
  if (tid < NB) cnt[tid] = 0;
  __syncthreads();
  for (int a = tid; a < NA; a += blockDim.x) {
    int zz = z[a];
    int b = (zz >= 8) ? 8 : zz;
    zb[a] = b;
    atomicAdd(&cnt[b], 1);
    double m = d_MASS[zz];
    wm[a] = 1.0/sqrt(m);
    minv[a] = 1.0/m;
  }
  __syncthreads();
  if (tid == 0) {
    int off = 0;
    for (int g = 0; g < NB; ++g) {
      desc[16+g] = 3*off;
      int ng = 3*cnt[g];
      int cap = (g < 8) ? CAPSM : CAP8;
      ng = (ng > cap) ? cap : ng;
      desc[g] = ng;
      desc[32+g] = ng + (ng & 1);
      int nb = (ng + 15)/16;
      if (nb & 1) nb++;
      desc[48+g] = nb;
      off += cnt[g];
    }
    desc[16+NB] = 3*off;
  }
  __syncthreads();
  for (int a = tid; a < NA; a += blockDim.x) {
    int b = zb[a]; int r = 0;
    for (int x = 0; x < a; ++x) r += (zb[x] == b) ? 1 : 0;
    if (r < 512) desc[64 + b*512 + r] = a;
  }
}

// ---------------- build sparse mass-weighted symmetrized H ----------------
__global__ void k_buildH(const int* __restrict__ ei, const float* __restrict__ Hi,
                         const float* __restrict__ Hij, char* ws) {
  int p = blockIdx.x, t = threadIdx.x;
  const double* wm = (const double*)(ws + O_WM);
  const double* minv = (const double*)(ws + O_MINV);
  int* hcol = (int*)(ws + O_HCOL);
  double* hv = (double*)(ws + O_HV64);
  float* hvf = (float*)(ws + O_HV32);
  __shared__ double rowabs[3][72];
  __shared__ double dcen[3];
  double v[9];
  int q = -1;
  if (t == 0) {
    q = p;
    double mi = minv[p];
    for (int a = 0; a < 3; ++a)
      for (int b = 0; b < 3; ++b)
        v[3*a+b] = 0.5*((double)Hi[9*p+3*a+b] + (double)Hi[9*p+3*b+a])*mi;
    for (int a = 0; a < 3; ++a) dcen[a] = v[3*a+a];
  } else if (t <= 32) {
    int off = t;
    int e = 32*p + off - 1;
    q = ei[e];
    double ww = 0.5*wm[p]*wm[q];
    for (int a = 0; a < 3; ++a)
      for (int b = 0; b < 3; ++b)
        v[3*a+b] = ww*(double)Hij[9*e+3*a+b];
  } else if (t <= 64) {
    int off = t - 32;
    int qr = (p + NA - off) % NA;
    int e = 32*qr + off - 1;
    q = ei[NEDGE + e];
    double ww = 0.5*wm[p]*wm[q];
    for (int a = 0; a < 3; ++a)
      for (int b = 0; b < 3; ++b)
        v[3*a+b] = ww*(double)Hij[9*e+3*b+a];
  }
  if (t < 65) {
    hcol[p*65+t] = q;
    for (int k = 0; k < 9; ++k) {
      hv[((size_t)p*65+t)*9+k] = v[k];
      hvf[((size_t)p*65+t)*12+k] = (float)v[k];
    }
    for (int k = 9; k < 12; ++k) hvf[((size_t)p*65+t)*12+k] = 0.0f;
    for (int a = 0; a < 3; ++a)
      rowabs[a][t] = fabs(v[3*a]) + fabs(v[3*a+1]) + fabs(v[3*a+2]);
  }
  __syncthreads();
  if (t == 0) {
    double hi = -1e300, lo = 1e300;
    for (int a = 0; a < 3; ++a) {
      double s = 0.0;
      for (int k = 0; k < 65; ++k) s += rowabs[a][k];
      double rad = s - fabs(dcen[a]);
      hi = fmax(hi, dcen[a] + rad);
      lo = fmin(lo, dcen[a] - rad);
    }
    double* ger = (double*)(ws + O_GER);
    ger[2*p] = hi; ger[2*p+1] = lo;
  }
}

// ---------------- spectrum bounds + Jackson-Chebyshev coefficients ----------------
__global__ void k_coeff(char* ws) {
  __shared__ double shi[256], slo[256];
  int tid = threadIdx.x;
  const double* ger = (const double*)(ws + O_GER);
  double hi = -1e300, lo = 1e300;
  for (int i = tid; i < NA; i += 256) { hi = fmax(hi, ger[2*i]); lo = fmin(lo, ger[2*i+1]); }
  shi[tid] = hi; slo[tid] = lo;
  __syncthreads();
  for (int s = 128; s > 0; s >>= 1) {
    if (tid < s) { shi[tid] = fmax(shi[tid], shi[tid+s]); slo[tid] = fmin(slo[tid], slo[tid+s]); }
    __syncthreads();
  }
  double* ch = (double*)(ws + O_CH);
  if (tid == 0) {
    double c = 0.5*(shi[0]+slo[0]);
    double h = 0.5*(shi[0]-slo[0])*1.002;
    ch[0] = c; ch[1] = h;
  }
  __syncthreads();
  double c = ch[0], h = ch[1];
  double* coef = (double*)(ws + O_COEF);
  for (int g = 0; g < NB; ++g) {
    int d = d_DEG[g];
    double xlo = fmin(1.0, fmax(-1.0, (d_BLO[g]-c)/h));
    double xhi = fmin(1.0, fmax(-1.0, (d_BHI[g]-c)/h));
    double f1 = acos(xlo), f2 = acos(xhi);
    double alp = PI_D/(double)(d+1);
    double ct = cos(alp)/sin(alp);
    for (int k = tid; k <= d; k += 256) {
      double ck = (k == 0) ? (f1-f2)/PI_D : 2.0*(sin(k*f1)-sin(k*f2))/(k*PI_D);
      double jk = ((double)(d+1-k)*cos(k*alp) + sin(k*alp)*ct)/(double)(d+1);
      coef[g*COEFLD+k] = ck*jk;
    }
  }
}

// ---------------- mass-weighted dipole/polar matrix Dt[4500][9] ----------------
__global__ void k_dt(const float* __restrict__ ded, const float* __restrict__ dep, char* ws) {
  int row = blockIdx.x*256 + threadIdx.x;
  if (row >= NDIM) return;
  int p = row/3, a = row%3;
  const double* wm = (const double*)(ws + O_WM);
  double w = wm[p];
  double* dt = (double*)(ws + O_DT) + (size_t)row*9;
  for (int cI = 0; cI < 3; ++cI) dt[cI] = w*(double)ded[9*p+3*a+cI];
  for (int cI = 0; cI < 6; ++cI) dt[3+cI] = w*(double)dep[18*p+6*a+cI];
}

// ---------------- scatter initial coordinate basis + gamma0 term into Y ----------------
__global__ void k_x0scatter(char* ws, int g, float* __restrict__ Tc) {
  const int* desc = (const int*)ws;
  int ng = desc[g];
  float* Y = (float*)(ws + O_Y);
  const double* coef = (const double*)(ws + O_COEF);
  float g0 = (float)coef[g*COEFLD+0];
  for (int jj = threadIdx.x; jj < ng; jj += blockDim.x) {
    int atom = desc[64 + g*512 + jj/3];
    int row = 3*atom + jj%3;
    Tc[(size_t)row*TLD + jj] = 1.0f;
    Y[(size_t)row*YLD + jj] = g0;
  }
}

// ---------------- one Chebyshev tile step (shared by coop & per-step kernels) ----------------
// Tile = PA(20) atoms x 64 cols; x-slab (255 rows x 64 cols) in LDS.
__device__ __forceinline__ void cheb_tile(char* ws, int ng, float cc, float hinv, float gam,
                                          int first, int tI, int ncg,
                                          const float* __restrict__ Tsrc,
                                          float* __restrict__ Tdst,
                                          float (*xs)[64]) {
  const float* __restrict__ hvf = (const float*)(ws + O_HV32);
  float* Y = (float*)(ws + O_Y);
  int tid = threadIdx.x, lane = tid & 63, w = tid >> 6;
  int ag = tI / ncg, cgp = tI - ag*ncg;
  int c0 = cgp << 6;
  if (c0 >= ng) return;            // block-uniform
  int a0 = ag*PA;
  // ---- stage x slab: atoms a0-32..a0+52 (255 rows), 64 cols ----
  {
    int cq = (lane & 15) << 2;
    int rbase = (w << 2) + (lane >> 4);
    #pragma unroll
    for (int i = 0; i < 16; ++i) {
      int r = (i << 4) + rbase;
      if (r < 255) {
        int ai = r/3, rr = r - ai*3;
        int am = a0 - 32 + ai;
        if (am < 0) am += NA;
        if (am >= NA) am -= NA;
        float4 vv = *(const float4*)(Tsrc + (size_t)(3*am+rr)*TLD + c0 + cq);
        *(float4*)&xs[r][cq] = vv;
      }
    }
  }
  __syncthreads();
  int col = c0 + lane;
  for (int pl = w*5; pl < w*5+5; ++pl) {
    int p = a0 + pl;
    const float* __restrict__ vb = hvf + (size_t)p*65*12;
    int sd = pl + 32;
    float xd0 = xs[3*sd][lane], xd1 = xs[3*sd+1][lane], xd2 = xs[3*sd+2][lane];
    float4 va = *(const float4*)vb;
    float4 vq = *(const float4*)(vb+4);
    float v8 = vb[8];
    float A0 = va.x*xd0 + va.y*xd1 + va.z*xd2;
    float A1 = va.w*xd0 + vq.x*xd1 + vq.y*xd2;
    float A2 = vq.z*xd0 + vq.w*xd1 + v8*xd2;
    #pragma unroll 8
    for (int t = 1; t <= 64; ++t) {
      int du = (t <= 32) ? t : (32 - t);
      int s = pl + 32 + du;
      float x0 = xs[3*s][lane], x1 = xs[3*s+1][lane], x2 = xs[3*s+2][lane];
      const float* v = vb + t*12;
      float4 wa = *(const float4*)v;
      float4 wq = *(const float4*)(v+4);
      float w8 = v[8];
      A0 += wa.x*x0 + wa.y*x1 + wa.z*x2;
      A1 += wa.w*x0 + wq.x*x1 + wq.y*x2;
      A2 += wq.z*x0 + wq.w*x1 + w8*x2;
    }
    if (col < ng) {
      float u0 = (A0 - cc*xd0)*hinv;
      float u1 = (A1 - cc*xd1)*hinv;
      float u2 = (A2 - cc*xd2)*hinv;
      size_t r0 = (size_t)(3*p)*TLD + col;
      float t0 = Tdst[r0], t1 = Tdst[r0+TLD], t2 = Tdst[r0+2*TLD];
      float n0 = first ? u0 : (2.0f*u0 - t0);
      float n1 = first ? u1 : (2.0f*u1 - t1);
      float n2 = first ? u2 : (2.0f*u2 - t2);
      Tdst[r0] = n0; Tdst[r0+TLD] = n1; Tdst[r0+2*TLD] = n2;
      size_t y0 = (size_t)(3*p)*YLD + col;
      Y[y0] += gam*n0; Y[y0+YLD] += gam*n1; Y[y0+2*YLD] += gam*n2;
    }
  }
  __syncthreads();
}

// ---------------- cooperative fused Chebyshev filter (whole band) ----------------
__global__ __launch_bounds__(256) void k_chebT(char* ws, int g, float* Ta, float* Tb) {
  cg::grid_group grid = cg::this_grid();
  __shared__ __align__(16) float xs[255][64];
  const int* desc = (const int*)ws;
  int ng = desc[g];
  int deg = d_DEG[g];
  const double* ch = (const double*)(ws + O_CH);
  float cc = (float)ch[0];
  float hinv = (float)(1.0/ch[1]);
  const double* coef = (const double*)(ws + O_COEF) + (size_t)g*COEFLD;
  int cap = (g < 8) ? CAPSM : CAP8;
  int ncg = cap >> 6;
  int ntile = NAG*ncg;
  for (int k = 1; k <= deg; ++k) {
    const float* Tsrc = (k & 1) ? Ta : Tb;
    float* Tdst = (k & 1) ? Tb : Ta;
    float gam = (float)coef[k];
    int first = (k == 1);
    for (int tI = blockIdx.x; tI < ntile; tI += CBGRID)
      cheb_tile(ws, ng, cc, hinv, gam, first, tI, ncg, Tsrc, Tdst, xs);
    grid.sync();
  }
}

// ---------------- per-step fallback (identical math, kernel-boundary sync) ----------------
__global__ __launch_bounds__(256) void k_chebS(char* ws, int g, int kstep, float* Ta, float* Tb) {
  __shared__ __align__(16) float xs[255][64];
  const int* desc = (const int*)ws;
  int ng = desc[g];
  const double* ch = (const double*)(ws + O_CH);
  float cc = (float)ch[0];
  float hinv = (float)(1.0/ch[1]);
  const double* coef = (const double*)(ws + O_COEF) + (size_t)g*COEFLD;
  int cap = (g < 8) ? CAPSM : CAP8;
  int ncg = cap >> 6;
  const float* Tsrc = (kstep & 1) ? Ta : Tb;
  float* Tdst = (kstep & 1) ? Tb : Ta;
  cheb_tile(ws, ng, cc, hinv, (float)coef[kstep], (kstep == 1) ? 1 : 0,
            blockIdx.x, ncg, Tsrc, Tdst, xs);
}

// ---------------- f64 SpMM: Z = H * X(cols c0..c0+cw) ----------------
__global__ __launch_bounds__(256) void k_spmm64(char* ws, const double* __restrict__ X,
                                                double* __restrict__ Z, int cw) {
  __shared__ double sval[585];
  __shared__ int scol[65];
  int p = blockIdx.x;
  const double* hv = (const double*)(ws + O_HV64) + (size_t)p*585;
  const int* hcol = (const int*)(ws + O_HCOL) + p*65;
  for (int l = threadIdx.x; l < 585; l += 256) sval[l] = hv[l];
  if (threadIdx.x < 65) scol[threadIdx.x] = hcol[threadIdx.x];
  __syncthreads();
  int col = blockIdx.y*256 + threadIdx.x;
  if (col >= cw) return;
  double a0 = 0.0, a1 = 0.0, a2 = 0.0;
  for (int t = 0; t < 65; ++t) {
    int q = scol[t];
    const double* xb = X + (size_t)(3*q)*YLD + col;
    double x0 = xb[0], x1 = xb[YLD], x2 = xb[2*YLD];
    const double* v = sval + t*9;
    a0 += v[0]*x0 + v[1]*x1 + v[2]*x2;
    a1 += v[3]*x0 + v[4]*x1 + v[5]*x2;
    a2 += v[6]*x0 + v[7]*x1 + v[8]*x2;
  }
  Z[(size_t)(3*p+0)*ZCHW + col] = a0;
  Z[(size_t)(3*p+1)*ZCHW + col] = a1;
  Z[(size_t)(3*p+2)*ZCHW + col] = a2;
}

// ---------------- Y (f32) -> X2 (f64) ----------------
__global__ void k_upcast(char* ws) {
  size_t i = (size_t)blockIdx.x*1024 + threadIdx.x;
  if (i < (size_t)NDIM*YLD)
    ((double*)(ws + O_X2))[i] = (double)((const float*)(ws + O_Y))[i];
}

// ---------------- f64 GEMMs: 64x64 tile, 4x4 micro-tile ----------------
__global__ __launch_bounds__(256) void gemm_tn(const double* __restrict__ A, const double* __restrict__ B,
                                               double* __restrict__ C,
                                               int M, int N, int K, int lda, int ldb, int ldc) {
  __shared__ double As[16][66];
  __shared__ double Bs[16][66];
  int tid = threadIdx.x;
  int tx = tid & 15, ty = tid >> 4;
  int i0 = blockIdx.x*64, j0 = blockIdx.y*64;
  double acc[4][4] = {};
  for (int k0 = 0; k0 < K; k0 += 16) {
    for (int l = tid; l < 1024; l += 256) {
      int r = l >> 6, c = l & 63;
      int kk = k0 + r;
      As[r][c] = (kk < K && i0+c < M) ? A[(size_t)kk*lda + i0+c] : 0.0;
    }
    for (int l = tid; l < 1024; l += 256) {
      int r = l >> 6, c = l & 63;
      int kk = k0 + r;
      Bs[r][c] = (kk < K && j0+c < N) ? B[(size_t)kk*ldb + j0+c] : 0.0;
    }
    __syncthreads();
    for (int kk = 0; kk < 16; ++kk) {
      double a[4], b[4];
      #pragma unroll
      for (int i = 0; i < 4; ++i) { a[i] = As[kk][4*ty+i]; b[i] = Bs[kk][4*tx+i]; }
      #pragma unroll
      for (int i = 0; i < 4; ++i)
        #pragma unroll
        for (int j = 0; j < 4; ++j) acc[i][j] += a[i]*b[j];
    }
    __syncthreads();
  }
  for (int i = 0; i < 4; ++i) {
    int ii = i0 + 4*ty + i;
    if (ii >= M) continue;
    for (int j = 0; j < 4; ++j) {
      int jj = j0 + 4*tx + j;
      if (jj < N) C[(size_t)ii*ldc + jj] = acc[i][j];
    }
  }
}

__global__ __launch_bounds__(256) void gemm_nn(const double* __restrict__ A, const double* __restrict__ B,
                                               double* __restrict__ C,
                                               int M, int N, int K, int lda, int ldb, int ldc) {
  __shared__ double As[16][66];
  __shared__ double Bs[16][66];
  int tid = threadIdx.x;
  int tx = tid & 15, ty = tid >> 4;
  int i0 = blockIdx.x*64, j0 = blockIdx.y*64;
  double acc[4][4] = {};
  for (int k0 = 0; k0 < K; k0 += 16) {
    for (int l = tid; l < 1024; l += 256) {
      int r = l & 15, c = l >> 4;
      As[r][c] = ((i0+c) < M && (k0+r) < K) ? A[(size_t)(i0+c)*lda + k0+r] : 0.0;
    }
    for (int l = tid; l < 1024; l += 256) {
      int r = l >> 6, c = l & 63;
      Bs[r][c] = ((k0+r) < K && (j0+c) < N) ? B[(size_t)(k0+r)*ldb + j0+c] : 0.0;
    }
    __syncthreads();
    for (int kk = 0; kk < 16; ++kk) {
      double a[4], b[4];
      #pragma unroll
      for (int i = 0; i < 4; ++i) { a[i] = As[kk][4*ty+i]; b[i] = Bs[kk][4*tx+i]; }
      #pragma unroll
      for (int i = 0; i < 4; ++i)
        #pragma unroll
        for (int j = 0; j < 4; ++j) acc[i][j] += a[i]*b[j];
    }
    __syncthreads();
  }
  for (int i = 0; i < 4; ++i) {
    int ii = i0 + 4*ty + i;
    if (ii >= M) continue;
    for (int j = 0; j < 4; ++j) {
      int jj = j0 + 4*tx + j;
      if (jj < N) C[(size_t)ii*ldc + jj] = acc[i][j];
    }
  }
}

__global__ void k_pbuild(double* P, const double* S, int cap) {
  size_t idx = (size_t)blockIdx.x*256 + threadIdx.x;
  if (idx >= (size_t)cap*cap) return;
  int r = (int)(idx / cap), cI = (int)(idx % cap);
  P[idx] = (15.0*(r==cI ? 1.0 : 0.0) - 10.0*S[idx] + 3.0*P[idx])*0.125;
}

__global__ void k_jinit(double* J, int cap) {
  size_t idx = (size_t)blockIdx.x*256 + threadIdx.x;
  if (idx >= (size_t)cap*cap) return;
  int r = (int)(idx / cap), cI = (int)(idx % cap);
  J[idx] = (r==cI) ? 1.0 : 0.0;
}

// ---------------- block one-sided Jacobi on all band Heffs (cooperative) ----------------
__global__ __launch_bounds__(256) void k_bjac(char* ws) {
  cg::grid_group grid = cg::this_grid();
  const int* desc = (const int*)ws;
  double* Gb = (double*)(ws + O_G);
  double* Jb = (double*)(ws + O_J);
  __shared__ double Wm[32][33];
  __shared__ double Vm[32][33];
  __shared__ double Cs[64][33];
  int tid = threadIdx.x;
  int tx = tid & 15, ty = tid >> 4;
  int mmax = 1;
  for (int g = 0; g < NB; ++g) {
    int nb = desc[48+g];
    if (nb >= 2 && nb-1 > mmax) mmax = nb-1;
  }
  int RT = SWEEPSB*mmax;
  for (int r = 0; r < RT; ++r) {
    int t = blockIdx.x;
    int g, k;
    if (t < 160) { g = t/20; k = t%20; } else { g = 8; k = t-160; }
    int nb = desc[48+g];
    int ng = desc[g];
    bool active = (nb >= 2);
    int m = active ? nb-1 : 1;
    if (!active || r >= SWEEPSB*m || k >= nb/2) active = false;
    if (active) {
      int rr = r % m;
      int I, J;
      if (k == 0) { I = m; J = rr; }
      else { I = (rr + k) % m; J = (rr + m - k) % m; }
      int cI = I*16, cJ = J*16;
      if (cI >= ng && cJ >= ng) active = false;
      if (active) {
        int cap = (g < 8) ? CAPSM : CAP8;
        size_t base = goffd(g);
        double* G = Gb + base;
        double* Jm2 = Jb + base;
        double w00=0.0, w01=0.0, w10=0.0, w11=0.0;
        for (int i0 = 0; i0 < ng; i0 += 64) {
          for (int l = tid; l < 2048; l += 256) {
            int rw = l & 63, j = l >> 6;
            int cidx = (j < 16) ? cI + j : cJ + (j-16);
            int i = i0 + rw;
            Cs[rw][j] = (i < ng) ? G[(size_t)cidx*cap + i] : 0.0;
          }
          __syncthreads();
          #pragma unroll 8
          for (int rw = 0; rw < 64; ++rw) {
            double a0 = Cs[rw][ty], a1 = Cs[rw][ty+16];
            double b0 = Cs[rw][tx], b1 = Cs[rw][tx+16];
            w00 += a0*b0; w01 += a0*b1; w10 += a1*b0; w11 += a1*b1;
          }
          __syncthreads();
        }
        Wm[ty][tx] = w00;      Wm[ty][tx+16] = w01;
        Wm[ty+16][tx] = w10;   Wm[ty+16][tx+16] = w11;
        Vm[ty][tx] = (ty==tx) ? 1.0 : 0.0;
        Vm[ty][tx+16] = 0.0;
        Vm[ty+16][tx] = 0.0;
        Vm[ty+16][tx+16] = (ty==tx) ? 1.0 : 0.0;
        __syncthreads();
        int pid = ty, sub = tx;
        for (int sw = 0; sw < NSWLOC; ++sw) {
          for (int rr2 = 0; rr2 < 31; ++rr2) {
            int p2, q2;
            if (pid == 0) { p2 = 31; q2 = rr2; }
            else { p2 = (rr2 + pid) % 31; q2 = (rr2 + 31 - pid) % 31; }
            double wpp = Wm[p2][p2], wqq = Wm[q2][q2], wpq = Wm[p2][q2];
            double cr = 1.0, sr = 0.0;
            bool rot = (wpq*wpq > 1e-28*fabs(wpp*wqq) + 1e-280);
            if (rot) {
              double tau = (wqq - wpp)/(2.0*wpq);
              double tt = (tau >= 0.0 ? 1.0 : -1.0)/(fabs(tau) + sqrt(1.0 + tau*tau));
              cr = 1.0/sqrt(1.0 + tt*tt);
              sr = tt*cr;
            }
            __syncthreads();
            if (rot) {
              #pragma unroll
              for (int cc = 0; cc < 2; ++cc) {
                int c2 = sub + 16*cc;
                double u = Wm[p2][c2], v = Wm[q2][c2];
                Wm[p2][c2] = cr*u - sr*v;
                Wm[q2][c2] = sr*u + cr*v;
              }
            }
            __syncthreads();
            if (rot) {
              #pragma unroll
              for (int cc = 0; cc < 2; ++cc) {
                int rw = sub + 16*cc;
                double u = Wm[rw][p2], v = Wm[rw][q2];
                Wm[rw][p2] = cr*u - sr*v;
                Wm[rw][q2] = sr*u + cr*v;
                u = Vm[rw][p2]; v = Vm[rw][q2];
                Vm[rw][p2] = cr*u - sr*v;
                Vm[rw][q2] = sr*u + cr*v;
              }
            }
            __syncthreads();
          }
        }
        for (int i = tid; i < ng; i += 256) {
          double bg[32];
          #pragma unroll 8
          for (int rw = 0; rw < 32; ++rw) {
            int cidx = (rw < 16) ? cI + rw : cJ + (rw-16);
            bg[rw] = G[(size_t)cidx*cap + i];
          }
          for (int p = 0; p < 32; ++p) {
            double s = 0.0;
            #pragma unroll 8
            for (int rw = 0; rw < 32; ++rw) s += bg[rw]*Vm[rw][p];
            int cidx = (p < 16) ? cI + p : cJ + (p-16);
            G[(size_t)cidx*cap + i] = s;
          }
          #pragma unroll 8
          for (int rw = 0; rw < 32; ++rw) {
            int cidx = (rw < 16) ? cI + rw : cJ + (rw-16);
            bg[rw] = Jm2[(size_t)cidx*cap + i];
          }
          for (int p = 0; p < 32; ++p) {
            double s = 0.0;
            #pragma unroll 8
            for (int rw = 0; rw < 32; ++rw) s += bg[rw]*Vm[rw][p];
            int cidx = (p < 16) ? cI + p : cJ + (p-16);
            Jm2[(size_t)cidx*cap + i] = s;
          }
        }
      }
    }
    grid.sync();
  }
}

// ---------------- eigenvalues: lambda_k = J_k . G_k ----------------
__global__ void k_eig(char* ws) {
  const int* desc = (const int*)ws;
  double* eva = (double*)(ws + O_EVA);
  int* sid = (int*)(ws + O_SID);
  int wv = (blockIdx.x*blockDim.x + threadIdx.x) >> 6;
  int lane = threadIdx.x & 63;
  if (wv >= SORTN) return;
  if (wv >= NDIM) {
    if (lane == 0) { eva[wv] = 1e300; sid[wv] = wv; }
    return;
  }
  int g = 0;
  while (g < 8 && wv >= desc[16+g+1]) ++g;
  int k = wv - desc[16+g];
  int cap = (g < 8) ? CAPSM : CAP8;
  int ng = desc[g];
  size_t base = goffd(g) + (size_t)k*cap;
  const double* G = (const double*)(ws + O_G) + base;
  const double* J = (const double*)(ws + O_J) + base;
  double acc = 0.0;
  for (int i = lane; i < ng; i += 64) acc += J[i]*G[i];
  for (int s = 32; s > 0; s >>= 1) acc += __shfl_xor(acc, s, 64);
  if (lane == 0) { eva[wv] = acc; sid[wv] = wv; }
}

// ---------------- single-block bitonic sort ----------------
__global__ void k_sort(char* ws) {
  double* key = (double*)(ws + O_EVA);
  int* val = (int*)(ws + O_SID);
  int tid = threadIdx.x;
  for (int size = 2; size <= SORTN; size <<= 1) {
    for (int stride = size >> 1; stride > 0; stride >>= 1) {
      __syncthreads();
      for (int t = tid; t < SORTN/2; t += 1024) {
        int i = 2*t - (t & (stride-1));
        int j = i + stride;
        bool up = ((i & size) == 0);
        double ki = key[i], kj = key[j];
        if ((ki > kj) == up) {
          key[i] = kj; key[j] = ki;
          int v = val[i]; val[i] = val[j]; val[j] = v;
        }
      }
    }
  }
}

// ---------------- final: freq, ir, raman ----------------
__global__ void k_final(char* ws, float* __restrict__ out) {
  int m = blockIdx.x*256 + threadIdx.x;
  if (m >= NOUT) return;
  const int* desc = (const int*)ws;
  const double* eva = (const double*)(ws + O_EVA);
  const int* sid = (const int*)(ws + O_SID);
  int s = m + 6;
  double lam = eva[s];
  int gid = sid[s];
  int g = 0;
  while (g < 8 && gid >= desc[16+g+1]) ++g;
  int k = gid - desc[16+g];
  const double* R = (const double*)(ws + O_RB) + ((size_t)g*1152 + k)*9;
  double q0 = R[0], q1 = R[1], q2 = R[2];
  double ir = 42.2561*(q0*q0 + q1*q1 + q2*q2);
  double xx = R[3], xy = R[4], yy = R[5], xz = R[6], zy = R[7], zz = R[8];
  double alpha = (xx + yy + zz)/3.0;
  double gsq = 0.5*((xx-yy)*(xx-yy) + (yy-zz)*(yy-zz) + (zz-xx)*(zz-xx))
             + 3.0*(xy*xy + xz*xz + zy*zy);
  double raman = (45.0*alpha*alpha + 7.0*gsq)*0.078424;
  double freq = sqrt(fmax(lam, 0.0)*9.375829e28)/(2.0*PI_D)/2.9979245800e10*0.965;
  out[m] = (float)freq;
  out[NOUT + m] = (float)ir;
  out[2*NOUT + m] = (float)raman;
}

__global__ void k_fail(float* out) {
  int i = blockIdx.x*256 + threadIdx.x;
  if (i < 3*NOUT) out[i] = -7777.0f;
}

// ---------------- host ----------------
extern "C" void kernel_launch(void* const* d_in, const int* in_sizes, int n_in,
                              void* d_out, int out_size, void* d_ws, size_t ws_size,
                              hipStream_t stream) {
  const int* z = (const int*)d_in[1];
  const int* ei = (const int*)d_in[2];
  const float* Hi = (const float*)d_in[3];
  const float* Hij = (const float*)d_in[4];
  const float* ded = (const float*)d_in[5];
  const float* dep = (const float*)d_in[6];
  float* out = (float*)d_out;
  char* ws = (char*)d_ws;

  if (ws_size < WS_NEED) {
    k_fail<<<(3*NOUT+255)/256, 256, 0, stream>>>(out);
    return;
  }

  hipMemsetAsync(ws, 0, O_HCOL, stream);
  k_prep<<<1, 256, 0, stream>>>(z, ws);
  k_buildH<<<NA, 128, 0, stream>>>(ei, Hi, Hij, ws);
  k_coeff<<<1, 256, 0, stream>>>(ws);
  k_dt<<<(NDIM+255)/256, 256, 0, stream>>>(ded, dep, ws);

  float* TP = (float*)(ws + O_X1);
  float* TC = (float*)(ws + O_X1 + (size_t)NDIM*TLD*4);
  double* X1 = (double*)(ws + O_X1);
  double* X2 = (double*)(ws + O_X2);
  double* Sb = (double*)(ws + O_S);
  double* Pb = (double*)(ws + O_P);
  double* Zb = (double*)(ws + O_S);
  double* Dt = (double*)(ws + O_DT);

  for (int g = 0; g < NB; ++g) {
    int cap = capb(g);
    hipMemsetAsync((void*)(ws + O_Y), 0, (size_t)NDIM*YLD*4, stream);
    hipMemsetAsync((void*)TP, 0, (size_t)NDIM*TLD*4, stream);
    hipMemsetAsync((void*)TC, 0, (size_t)NDIM*TLD*4, stream);
    k_x0scatter<<<1, 1024, 0, stream>>>(ws, g, TC);
    {
      float* Ta = TC; float* Tb = TP;
      void* args[] = { (void*)&ws, (void*)&g, (void*)&Ta, (void*)&Tb };
      hipError_t ce = hipLaunchCooperativeKernel((void*)k_chebT, dim3(CBGRID), dim3(256), args, 0, stream);
      if (ce != hipSuccess) {
        (void)hipGetLastError();
        int ncg = cap >> 6;
        int ntile = NAG*ncg;
        for (int k = 1; k <= H_DEG[g]; ++k)
          k_chebS<<<ntile, 256, 0, stream>>>(ws, g, k, Ta, Tb);
      }
    }
    k_upcast<<<(NDIM*YLD + 1023)/1024, 1024, 0, stream>>>(ws);
    // Newton-Schulz orthonormalization (5 iters), ping-pong X2 <-> X1
    double* Xa = X2; double* Xb = X1;
    dim3 gsq((cap+63)/64, (cap+63)/64);
    for (int it = 0; it < 5; ++it) {
      gemm_tn<<<gsq, 256, 0, stream>>>(Xa, Xa, Sb, cap, cap, NDIM, YLD, YLD, cap);
      gemm_nn<<<gsq, 256, 0, stream>>>(Sb, Sb, Pb, cap, cap, cap, cap, cap, cap);
      k_pbuild<<<((size_t)cap*cap + 255)/256, 256, 0, stream>>>(Pb, Sb, cap);
      gemm_nn<<<dim3((NDIM+63)/64, (cap+63)/64), 256, 0, stream>>>(Xa, Pb, Xb, NDIM, cap, cap, YLD, cap, YLD);
      double* tmp = Xa; Xa = Xb; Xb = tmp;
    }
    // PD_g = X^T Dt
    gemm_tn<<<dim3((cap+63)/64, 1), 256, 0, stream>>>(Xa, Dt,
        (double*)(ws + O_PD) + (size_t)g*1152*9, cap, 9, NDIM, YLD, 9, 9);
    // Heff_g = X^T (H X)  chunked
    double* Gg = (double*)(ws + O_G) + goffd(g);
    for (int zc = 0; zc < 2; ++zc) {
      int c0 = zc*ZCHW;
      int cwz = cap - c0; if (cwz > ZCHW) cwz = ZCHW;
      if (cwz <= 0) break;
      dim3 gz(NA, (cwz + 255)/256);
      k_spmm64<<<gz, 256, 0, stream>>>(ws, Xa + c0, Zb, cwz);
      gemm_tn<<<dim3((cap+63)/64, (cwz+63)/64), 256, 0, stream>>>(Xa, Zb, Gg + c0,
          cap, cwz, NDIM, YLD, ZCHW, cap);
    }
    k_jinit<<<((size_t)cap*cap + 255)/256, 256, 0, stream>>>((double*)(ws + O_J) + goffd(g), cap);
  }

  // joint block one-sided Jacobi on all bands
  {
    void* args[] = { (void*)&ws };
    hipLaunchCooperativeKernel((void*)k_bjac, dim3(TSLOTS), dim3(256), args, 0, stream);
  }

  k_eig<<<(SORTN*64)/256, 256, 0, stream>>>(ws);
  k_sort<<<1, 1024, 0, stream>>>(ws);

  for (int g = 0; g < NB; ++g) {
    int cap = capb(g);
    gemm_nn<<<dim3((cap+63)/64, 1), 256, 0, stream>>>(
        (double*)(ws + O_J) + goffd(g),
        (double*)(ws + O_PD) + (size_t)g*1152*9,
        (double*)(ws + O_RB) + (size_t)g*1152*9,
        cap, 9, cap, cap, 9, 9);
  }
  k_final<<<(NOUT+255)/256, 256, 0, stream>>>(ws, out);
}

// Round 6
// 525125.684 us; speedup vs baseline: 1.6318x; 1.6318x over previous
//
#include <hip/hip_runtime.h>
#include <hip/hip_cooperative_groups.h>
#include <math.h>

namespace cg = cooperative_groups;

#define NA      1500
#define NEDGE   48000
#define NDIM    4500
#define NB      9
#define TLD     1152
#define ZCHW    576
#define YLD     1152
#define CAPSM   640
#define CAP8    1152
#define SWEEPSB 8
#define NSWLOC  8
#define TSLOTS  196
#define SORTN   8192
#define COEFLD  864
#define NOUT    4494
#define PGRP    4
#define PI_D    3.14159265358979323846

// Chebyshev filter degrees (reduced ~0.62x: transition width ~ 2*37/d still < each gap)
static const int H_DEG[NB] = {24, 48, 96, 160, 320, 320, 336, 336, 272};
__device__ __constant__ int d_DEG[NB] = {24, 48, 96, 160, 320, 320, 336, 336, 272};
__device__ __constant__ double d_MASS[10] = {1.008,4.003,6.941,9.012,10.811,12.011,14.007,15.999,18.998,20.18};
// Voronoi band intervals in eigenvalue space (band 8 = merged z=8,9)
__device__ __constant__ double d_BLO[NB] = {31.04695, 9.84715, 6.37590, 5.08655, 4.39385, 3.86620, 3.34740, 2.87855, -1.0e9};
__device__ __constant__ double d_BHI[NB] = {1.0e9, 31.04695, 9.84715, 6.37590, 5.08655, 4.39385, 3.86620, 3.34740, 2.87855};

// ---------------- workspace layout (bytes) ----------------
constexpr size_t O_DESC = 0;
constexpr size_t O_WM   = 32768;                         // f64[1536]  1/sqrt(m) per atom
constexpr size_t O_MINV = O_WM + 12288;                  // f64[1536]  1/m per atom
constexpr size_t O_GER  = O_MINV + 12288;                // f64[2*1500] gersh hi/lo per atom
constexpr size_t O_CH   = O_GER + 24576;                 // f64: c, h
constexpr size_t O_COEF = O_CH + 256;                    // f64[9*864]
constexpr size_t O_DT   = O_COEF + (size_t)NB*COEFLD*8;  // f64[4500*9]
constexpr size_t O_PD   = O_DT + (size_t)NDIM*9*8;       // f64[9*1152*9]
constexpr size_t O_RB   = O_PD + (size_t)NB*1152*9*8;    // f64[9*1152*9]
constexpr size_t O_EVA  = O_RB + (size_t)NB*1152*9*8;    // f64[8192]
constexpr size_t O_SID  = O_EVA + (size_t)SORTN*8;       // int[8192]
constexpr size_t O_HCOL = O_SID + (size_t)SORTN*4;       // int[1500*65]
constexpr size_t O_HV64 = O_HCOL + (size_t)NA*65*4;      // f64[1500*65*9]
constexpr size_t O_HV32 = O_HV64 + (size_t)NA*65*9*8;    // f32[1500*65*12] (12-padded rows, 16B-aligned)
constexpr size_t O_Y    = O_HV32 + (size_t)NA*65*12*4;   // f32[4500*1152]
constexpr size_t O_X1   = O_Y + (size_t)NDIM*YLD*4;      // f64[4500*1152]; aliases TP/TC f32 bufs
constexpr size_t O_X2   = O_X1 + (size_t)NDIM*YLD*8;     // f64[4500*1152]
constexpr size_t O_S    = O_X2 + (size_t)NDIM*YLD*8;     // f64[1152^2]; Z chunk aliases S..P
constexpr size_t O_P    = O_S + (size_t)CAP8*CAP8*8;     // f64[1152^2]
constexpr size_t O_G    = O_P + (size_t)CAP8*CAP8*8;     // f64[8*640^2 + 1152^2]
constexpr size_t GTOT   = (size_t)8*CAPSM*CAPSM + (size_t)CAP8*CAP8;
constexpr size_t O_J    = O_G + GTOT*8;
constexpr size_t WS_NEED = O_J + GTOT*8;                 // ~213 MB

__host__ __device__ inline size_t goffd(int g){ return (g < 8) ? (size_t)g*CAPSM*CAPSM : (size_t)8*CAPSM*CAPSM; }
__host__ inline int capb(int g){ return (g < 8) ? CAPSM : CAP8; }

// ---------------- prep ----------------
__global__ void k_prep(const int* __restrict__ z, char* ws) {
  int* desc = (int*)ws;
  double* wm = (double*)(ws + O_WM);
  double* minv = (double*)(ws + O_MINV);
  __shared__ int zb[NA];
  __shared__ int cnt[NB];
  int tid = threadIdx.x;
  if (tid < NB) cnt[tid] = 0;
  __syncthreads();
  for (int a = tid; a < NA; a += blockDim.x) {
    int zz = z[a];
    int b = (zz >= 8) ? 8 : zz;
    zb[a] = b;
    atomicAdd(&cnt[b], 1);
    double m = d_MASS[zz];
    wm[a] = 1.0/sqrt(m);
    minv[a] = 1.0/m;
  }
  __syncthreads();
  if (tid == 0) {
    int off = 0;
    for (int g = 0; g < NB; ++g) {
      desc[16+g] = 3*off;
      int ng = 3*cnt[g];
      int cap = (g < 8) ? CAPSM : CAP8;
      ng = (ng > cap) ? cap : ng;
      desc[g] = ng;
      desc[32+g] = ng + (ng & 1);
      int nb = (ng + 15)/16;
      if (nb & 1) nb++;
      desc[48+g] = nb;
      off += cnt[g];
    }
    desc[16+NB] = 3*off;
  }
  __syncthreads();
  for (int a = tid; a < NA; a += blockDim.x) {
    int b = zb[a]; int r = 0;
    for (int x = 0; x < a; ++x) r += (zb[x] == b) ? 1 : 0;
    if (r < 512) desc[64 + b*512 + r] = a;
  }
}

// ---------------- build sparse mass-weighted symmetrized H ----------------
__global__ void k_buildH(const int* __restrict__ ei, const float* __restrict__ Hi,
                         const float* __restrict__ Hij, char* ws) {
  int p = blockIdx.x, t = threadIdx.x;
  const double* wm = (const double*)(ws + O_WM);
  const double* minv = (const double*)(ws + O_MINV);
  int* hcol = (int*)(ws + O_HCOL);
  double* hv = (double*)(ws + O_HV64);
  float* hvf = (float*)(ws + O_HV32);
  __shared__ double rowabs[3][72];
  __shared__ double dcen[3];
  double v[9];
  int q = -1;
  if (t == 0) {
    q = p;
    double mi = minv[p];
    for (int a = 0; a < 3; ++a)
      for (int b = 0; b < 3; ++b)
        v[3*a+b] = 0.5*((double)Hi[9*p+3*a+b] + (double)Hi[9*p+3*b+a])*mi;
    for (int a = 0; a < 3; ++a) dcen[a] = v[3*a+a];
  } else if (t <= 32) {
    int off = t;
    int e = 32*p + off - 1;
    q = ei[e];
    double ww = 0.5*wm[p]*wm[q];
    for (int a = 0; a < 3; ++a)
      for (int b = 0; b < 3; ++b)
        v[3*a+b] = ww*(double)Hij[9*e+3*a+b];
  } else if (t <= 64) {
    int off = t - 32;
    int qr = (p + NA - off) % NA;
    int e = 32*qr + off - 1;
    q = ei[NEDGE + e];
    double ww = 0.5*wm[p]*wm[q];
    for (int a = 0; a < 3; ++a)
      for (int b = 0; b < 3; ++b)
        v[3*a+b] = ww*(double)Hij[9*e+3*b+a];
  }
  if (t < 65) {
    hcol[p*65+t] = q;
    for (int k = 0; k < 9; ++k) {
      hv[((size_t)p*65+t)*9+k] = v[k];
      hvf[((size_t)p*65+t)*12+k] = (float)v[k];
    }
    for (int k = 9; k < 12; ++k) hvf[((size_t)p*65+t)*12+k] = 0.0f;
    for (int a = 0; a < 3; ++a)
      rowabs[a][t] = fabs(v[3*a]) + fabs(v[3*a+1]) + fabs(v[3*a+2]);
  }
  __syncthreads();
  if (t == 0) {
    double hi = -1e300, lo = 1e300;
    for (int a = 0; a < 3; ++a) {
      double s = 0.0;
      for (int k = 0; k < 65; ++k) s += rowabs[a][k];
      double rad = s - fabs(dcen[a]);
      hi = fmax(hi, dcen[a] + rad);
      lo = fmin(lo, dcen[a] - rad);
    }
    double* ger = (double*)(ws + O_GER);
    ger[2*p] = hi; ger[2*p+1] = lo;
  }
}

// ---------------- spectrum bounds + Jackson-Chebyshev coefficients ----------------
__global__ void k_coeff(char* ws) {
  __shared__ double shi[256], slo[256];
  int tid = threadIdx.x;
  const double* ger = (const double*)(ws + O_GER);
  double hi = -1e300, lo = 1e300;
  for (int i = tid; i < NA; i += 256) { hi = fmax(hi, ger[2*i]); lo = fmin(lo, ger[2*i+1]); }
  shi[tid] = hi; slo[tid] = lo;
  __syncthreads();
  for (int s = 128; s > 0; s >>= 1) {
    if (tid < s) { shi[tid] = fmax(shi[tid], shi[tid+s]); slo[tid] = fmin(slo[tid], slo[tid+s]); }
    __syncthreads();
  }
  double* ch = (double*)(ws + O_CH);
  if (tid == 0) {
    double c = 0.5*(shi[0]+slo[0]);
    double h = 0.5*(shi[0]-slo[0])*1.002;
    ch[0] = c; ch[1] = h;
  }
  __syncthreads();
  double c = ch[0], h = ch[1];
  double* coef = (double*)(ws + O_COEF);
  for (int g = 0; g < NB; ++g) {
    int d = d_DEG[g];
    double xlo = fmin(1.0, fmax(-1.0, (d_BLO[g]-c)/h));
    double xhi = fmin(1.0, fmax(-1.0, (d_BHI[g]-c)/h));
    double f1 = acos(xlo), f2 = acos(xhi);
    double alp = PI_D/(double)(d+1);
    double ct = cos(alp)/sin(alp);
    for (int k = tid; k <= d; k += 256) {
      double ck = (k == 0) ? (f1-f2)/PI_D : 2.0*(sin(k*f1)-sin(k*f2))/(k*PI_D);
      double jk = ((double)(d+1-k)*cos(k*alp) + sin(k*alp)*ct)/(double)(d+1);
      coef[g*COEFLD+k] = ck*jk;
    }
  }
}

// ---------------- mass-weighted dipole/polar matrix Dt[4500][9] ----------------
__global__ void k_dt(const float* __restrict__ ded, const float* __restrict__ dep, char* ws) {
  int row = blockIdx.x*256 + threadIdx.x;
  if (row >= NDIM) return;
  int p = row/3, a = row%3;
  const double* wm = (const double*)(ws + O_WM);
  double w = wm[p];
  double* dt = (double*)(ws + O_DT) + (size_t)row*9;
  for (int cI = 0; cI < 3; ++cI) dt[cI] = w*(double)ded[9*p+3*a+cI];
  for (int cI = 0; cI < 6; ++cI) dt[3+cI] = w*(double)dep[18*p+6*a+cI];
}

// ---------------- scatter initial coordinate basis + gamma0 term into Y ----------------
__global__ void k_x0scatter(char* ws, int g, float* __restrict__ Tc) {
  const int* desc = (const int*)ws;
  int ng = desc[g];
  float* Y = (float*)(ws + O_Y);
  const double* coef = (const double*)(ws + O_COEF);
  float g0 = (float)coef[g*COEFLD+0];
  for (int jj = threadIdx.x; jj < ng; jj += blockDim.x) {
    int atom = desc[64 + g*512 + jj/3];
    int row = 3*atom + jj%3;
    Tc[(size_t)row*TLD + jj] = 1.0f;
    Y[(size_t)row*YLD + jj] = g0;
  }
}

// ---------------- Chebyshev step: 4-atom group, 2 cols/thread, b128 LDS v-loads ----------------
// Tdst = 2*Hhat*Tsrc - Tdst (first: = Hhat*Tsrc);  Y += gamma*Tdst
__global__ __launch_bounds__(256) void k_cheb(char* ws, int g, int kstep,
                                              const float* __restrict__ Tsrc,
                                              float* __restrict__ Tdst, int first) {
  __shared__ __align__(16) float sval[PGRP][780];   // 65 blocks * 12-padded
  int p0 = blockIdx.x*PGRP;
  {
    const float4* src4 = (const float4*)((const float*)(ws + O_HV32) + (size_t)p0*780);
    float4* dst4 = (float4*)&sval[0][0];
    for (int l = threadIdx.x; l < PGRP*195; l += 256) dst4[l] = src4[l];
  }
  __syncthreads();
  int ng = ((const int*)ws)[g];
  int c0 = blockIdx.y*512;
  int col0 = c0 + (int)threadIdx.x;
  int col1 = col0 + 256;
  bool v0ok = (col0 < ng);
  bool v1ok = (col1 < ng);
  int col1c = v1ok ? col1 : col0;
  const double* ch = (const double*)(ws + O_CH);
  float cc = (float)ch[0];
  float hinv = (float)(1.0/ch[1]);
  float gam = (float)((const double*)(ws + O_COEF))[g*COEFLD + kstep];
  float acc0[PGRP][3] = {}, acc1[PGRP][3] = {};
  float xd0[PGRP][3], xd1[PGRP][3];
  for (int du = -32; du <= 32 + (PGRP-1); ++du) {
    int u = p0 + du;
    if (u < 0) u += NA;
    if (u >= NA) u -= NA;
    const float* xb = Tsrc + (size_t)(3*u)*TLD;
    float a0 = xb[col0], a1 = xb[TLD+col0], a2 = xb[2*TLD+col0];
    float b0 = xb[col1c], b1 = xb[TLD+col1c], b2 = xb[2*TLD+col1c];
    #pragma unroll
    for (int pp = 0; pp < PGRP; ++pp) {
      int off = du - pp;
      int t;
      if (off == 0) {
        t = 0;
        xd0[pp][0] = a0; xd0[pp][1] = a1; xd0[pp][2] = a2;
        xd1[pp][0] = b0; xd1[pp][1] = b1; xd1[pp][2] = b2;
      }
      else if (off >= 1 && off <= 32) t = off;
      else if (off >= -32 && off <= -1) t = 32 - off;
      else continue;
      const float* v = &sval[pp][t*12];
      float4 va = *(const float4*)v;
      float4 vb = *(const float4*)(v+4);
      float v8 = v[8];
      acc0[pp][0] += va.x*a0 + va.y*a1 + va.z*a2;
      acc0[pp][1] += va.w*a0 + vb.x*a1 + vb.y*a2;
      acc0[pp][2] += vb.z*a0 + vb.w*a1 + v8*a2;
      acc1[pp][0] += va.x*b0 + va.y*b1 + va.z*b2;
      acc1[pp][1] += va.w*b0 + vb.x*b1 + vb.y*b2;
      acc1[pp][2] += vb.z*b0 + vb.w*b1 + v8*b2;
    }
  }
  float* Y = (float*)(ws + O_Y);
  #pragma unroll
  for (int pp = 0; pp < PGRP; ++pp) {
    int p = p0 + pp;
    #pragma unroll
    for (int a = 0; a < 3; ++a) {
      size_t rbase = (size_t)(3*p+a)*TLD;
      size_t ybase = (size_t)(3*p+a)*YLD;
      if (v0ok) {
        float u = (acc0[pp][a] - cc*xd0[pp][a])*hinv;
        float tp = Tdst[rbase + col0];
        float tn = first ? u : (2.0f*u - tp);
        Tdst[rbase + col0] = tn;
        Y[ybase + col0] += gam*tn;
      }
      if (v1ok) {
        float u = (acc1[pp][a] - cc*xd1[pp][a])*hinv;
        float tp = Tdst[rbase + col1];
        float tn = first ? u : (2.0f*u - tp);
        Tdst[rbase + col1] = tn;
        Y[ybase + col1] += gam*tn;
      }
    }
  }
}

// ---------------- f64 SpMM: Z = H * X(cols c0..c0+cw) ----------------
__global__ __launch_bounds__(256) void k_spmm64(char* ws, const double* __restrict__ X,
                                                double* __restrict__ Z, int cw) {
  __shared__ double sval[585];
  __shared__ int scol[65];
  int p = blockIdx.x;
  const double* hv = (const double*)(ws + O_HV64) + (size_t)p*585;
  const int* hcol = (const int*)(ws + O_HCOL) + p*65;
  for (int l = threadIdx.x; l < 585; l += 256) sval[l] = hv[l];
  if (threadIdx.x < 65) scol[threadIdx.x] = hcol[threadIdx.x];
  __syncthreads();
  int col = blockIdx.y*256 + threadIdx.x;
  if (col >= cw) return;
  double a0 = 0.0, a1 = 0.0, a2 = 0.0;
  for (int t = 0; t < 65; ++t) {
    int q = scol[t];
    const double* xb = X + (size_t)(3*q)*YLD + col;
    double x0 = xb[0], x1 = xb[YLD], x2 = xb[2*YLD];
    const double* v = sval + t*9;
    a0 += v[0]*x0 + v[1]*x1 + v[2]*x2;
    a1 += v[3]*x0 + v[4]*x1 + v[5]*x2;
    a2 += v[6]*x0 + v[7]*x1 + v[8]*x2;
  }
  Z[(size_t)(3*p+0)*ZCHW + col] = a0;
  Z[(size_t)(3*p+1)*ZCHW + col] = a1;
  Z[(size_t)(3*p+2)*ZCHW + col] = a2;
}

// ---------------- Y (f32) -> X2 (f64) ----------------
__global__ void k_upcast(char* ws) {
  size_t i = (size_t)blockIdx.x*1024 + threadIdx.x;
  if (i < (size_t)NDIM*YLD)
    ((double*)(ws + O_X2))[i] = (double)((const float*)(ws + O_Y))[i];
}

// ---------------- f64 GEMMs: 64x64 tile, 4x4 micro-tile ----------------
__global__ __launch_bounds__(256) void gemm_tn(const double* __restrict__ A, const double* __restrict__ B,
                                               double* __restrict__ C,
                                               int M, int N, int K, int lda, int ldb, int ldc) {
  __shared__ double As[16][66];
  __shared__ double Bs[16][66];
  int tid = threadIdx.x;
  int tx = tid & 15, ty = tid >> 4;
  int i0 = blockIdx.x*64, j0 = blockIdx.y*64;
  double acc[4][4] = {};
  for (int k0 = 0; k0 < K; k0 += 16) {
    for (int l = tid; l < 1024; l += 256) {
      int r = l >> 6, c = l & 63;
      int kk = k0 + r;
      As[r][c] = (kk < K && i0+c < M) ? A[(size_t)kk*lda + i0+c] : 0.0;
    }
    for (int l = tid; l < 1024; l += 256) {
      int r = l >> 6, c = l & 63;
      int kk = k0 + r;
      Bs[r][c] = (kk < K && j0+c < N) ? B[(size_t)kk*ldb + j0+c] : 0.0;
    }
    __syncthreads();
    for (int kk = 0; kk < 16; ++kk) {
      double a[4], b[4];
      #pragma unroll
      for (int i = 0; i < 4; ++i) { a[i] = As[kk][4*ty+i]; b[i] = Bs[kk][4*tx+i]; }
      #pragma unroll
      for (int i = 0; i < 4; ++i)
        #pragma unroll
        for (int j = 0; j < 4; ++j) acc[i][j] += a[i]*b[j];
    }
    __syncthreads();
  }
  for (int i = 0; i < 4; ++i) {
    int ii = i0 + 4*ty + i;
    if (ii >= M) continue;
    for (int j = 0; j < 4; ++j) {
      int jj = j0 + 4*tx + j;
      if (jj < N) C[(size_t)ii*ldc + jj] = acc[i][j];
    }
  }
}

__global__ __launch_bounds__(256) void gemm_nn(const double* __restrict__ A, const double* __restrict__ B,
                                               double* __restrict__ C,
                                               int M, int N, int K, int lda, int ldb, int ldc) {
  __shared__ double As[16][66];
  __shared__ double Bs[16][66];
  int tid = threadIdx.x;
  int tx = tid & 15, ty = tid >> 4;
  int i0 = blockIdx.x*64, j0 = blockIdx.y*64;
  double acc[4][4] = {};
  for (int k0 = 0; k0 < K; k0 += 16) {
    for (int l = tid; l < 1024; l += 256) {
      int r = l & 15, c = l >> 4;
      As[r][c] = ((i0+c) < M && (k0+r) < K) ? A[(size_t)(i0+c)*lda + k0+r] : 0.0;
    }
    for (int l = tid; l < 1024; l += 256) {
      int r = l >> 6, c = l & 63;
      Bs[r][c] = ((k0+r) < K && (j0+c) < N) ? B[(size_t)(k0+r)*ldb + j0+c] : 0.0;
    }
    __syncthreads();
    for (int kk = 0; kk < 16; ++kk) {
      double a[4], b[4];
      #pragma unroll
      for (int i = 0; i < 4; ++i) { a[i] = As[kk][4*ty+i]; b[i] = Bs[kk][4*tx+i]; }
      #pragma unroll
      for (int i = 0; i < 4; ++i)
        #pragma unroll
        for (int j = 0; j < 4; ++j) acc[i][j] += a[i]*b[j];
    }
    __syncthreads();
  }
  for (int i = 0; i < 4; ++i) {
    int ii = i0 + 4*ty + i;
    if (ii >= M) continue;
    for (int j = 0; j < 4; ++j) {
      int jj = j0 + 4*tx + j;
      if (jj < N) C[(size_t)ii*ldc + jj] = acc[i][j];
    }
  }
}

__global__ void k_pbuild(double* P, const double* S, int cap) {
  size_t idx = (size_t)blockIdx.x*256 + threadIdx.x;
  if (idx >= (size_t)cap*cap) return;
  int r = (int)(idx / cap), cI = (int)(idx % cap);
  P[idx] = (15.0*(r==cI ? 1.0 : 0.0) - 10.0*S[idx] + 3.0*P[idx])*0.125;
}

__global__ void k_jinit(double* J, int cap) {
  size_t idx = (size_t)blockIdx.x*256 + threadIdx.x;
  if (idx >= (size_t)cap*cap) return;
  int r = (int)(idx / cap), cI = (int)(idx % cap);
  J[idx] = (r==cI) ? 1.0 : 0.0;
}

// ---------------- block one-sided Jacobi on all band Heffs (cooperative) ----------------
__global__ __launch_bounds__(256) void k_bjac(char* ws) {
  cg::grid_group grid = cg::this_grid();
  const int* desc = (const int*)ws;
  double* Gb = (double*)(ws + O_G);
  double* Jb = (double*)(ws + O_J);
  __shared__ double Wm[32][33];
  __shared__ double Vm[32][33];
  __shared__ double Cs[64][33];
  int tid = threadIdx.x;
  int tx = tid & 15, ty = tid >> 4;
  int mmax = 1;
  for (int g = 0; g < NB; ++g) {
    int nb = desc[48+g];
    if (nb >= 2 && nb-1 > mmax) mmax = nb-1;
  }
  int RT = SWEEPSB*mmax;
  for (int r = 0; r < RT; ++r) {
    int t = blockIdx.x;
    int g, k;
    if (t < 160) { g = t/20; k = t%20; } else { g = 8; k = t-160; }
    int nb = desc[48+g];
    int ng = desc[g];
    bool active = (nb >= 2);
    int m = active ? nb-1 : 1;
    if (!active || r >= SWEEPSB*m || k >= nb/2) active = false;
    if (active) {
      int rr = r % m;
      int I, J;
      if (k == 0) { I = m; J = rr; }
      else { I = (rr + k) % m; J = (rr + m - k) % m; }
      int cI = I*16, cJ = J*16;
      if (cI >= ng && cJ >= ng) active = false;
      if (active) {
        int cap = (g < 8) ? CAPSM : CAP8;
        size_t base = goffd(g);
        double* G = Gb + base;
        double* Jm2 = Jb + base;
        double w00=0.0, w01=0.0, w10=0.0, w11=0.0;
        for (int i0 = 0; i0 < ng; i0 += 64) {
          for (int l = tid; l < 2048; l += 256) {
            int rw = l & 63, j = l >> 6;
            int cidx = (j < 16) ? cI + j : cJ + (j-16);
            int i = i0 + rw;
            Cs[rw][j] = (i < ng) ? G[(size_t)cidx*cap + i] : 0.0;
          }
          __syncthreads();
          #pragma unroll 8
          for (int rw = 0; rw < 64; ++rw) {
            double a0 = Cs[rw][ty], a1 = Cs[rw][ty+16];
            double b0 = Cs[rw][tx], b1 = Cs[rw][tx+16];
            w00 += a0*b0; w01 += a0*b1; w10 += a1*b0; w11 += a1*b1;
          }
          __syncthreads();
        }
        Wm[ty][tx] = w00;      Wm[ty][tx+16] = w01;
        Wm[ty+16][tx] = w10;   Wm[ty+16][tx+16] = w11;
        Vm[ty][tx] = (ty==tx) ? 1.0 : 0.0;
        Vm[ty][tx+16] = 0.0;
        Vm[ty+16][tx] = 0.0;
        Vm[ty+16][tx+16] = (ty==tx) ? 1.0 : 0.0;
        __syncthreads();
        int pid = ty, sub = tx;
        for (int sw = 0; sw < NSWLOC; ++sw) {
          for (int rr2 = 0; rr2 < 31; ++rr2) {
            int p2, q2;
            if (pid == 0) { p2 = 31; q2 = rr2; }
            else { p2 = (rr2 + pid) % 31; q2 = (rr2 + 31 - pid) % 31; }
            double wpp = Wm[p2][p2], wqq = Wm[q2][q2], wpq = Wm[p2][q2];
            double cr = 1.0, sr = 0.0;
            bool rot = (wpq*wpq > 1e-28*fabs(wpp*wqq) + 1e-280);
            if (rot) {
              double tau = (wqq - wpp)/(2.0*wpq);
              double tt = (tau >= 0.0 ? 1.0 : -1.0)/(fabs(tau) + sqrt(1.0 + tau*tau));
              cr = 1.0/sqrt(1.0 + tt*tt);
              sr = tt*cr;
            }
            __syncthreads();
            if (rot) {
              #pragma unroll
              for (int cc2 = 0; cc2 < 2; ++cc2) {
                int c2 = sub + 16*cc2;
                double u = Wm[p2][c2], v = Wm[q2][c2];
                Wm[p2][c2] = cr*u - sr*v;
                Wm[q2][c2] = sr*u + cr*v;
              }
            }
            __syncthreads();
            if (rot) {
              #pragma unroll
              for (int cc2 = 0; cc2 < 2; ++cc2) {
                int rw = sub + 16*cc2;
                double u = Wm[rw][p2], v = Wm[rw][q2];
                Wm[rw][p2] = cr*u - sr*v;
                Wm[rw][q2] = sr*u + cr*v;
                u = Vm[rw][p2]; v = Vm[rw][q2];
                Vm[rw][p2] = cr*u - sr*v;
                Vm[rw][q2] = sr*u + cr*v;
              }
            }
            __syncthreads();
          }
        }
        for (int i = tid; i < ng; i += 256) {
          double bg[32];
          #pragma unroll 8
          for (int rw = 0; rw < 32; ++rw) {
            int cidx = (rw < 16) ? cI + rw : cJ + (rw-16);
            bg[rw] = G[(size_t)cidx*cap + i];
          }
          for (int p = 0; p < 32; ++p) {
            double s = 0.0;
            #pragma unroll 8
            for (int rw = 0; rw < 32; ++rw) s += bg[rw]*Vm[rw][p];
            int cidx = (p < 16) ? cI + p : cJ + (p-16);
            G[(size_t)cidx*cap + i] = s;
          }
          #pragma unroll 8
          for (int rw = 0; rw < 32; ++rw) {
            int cidx = (rw < 16) ? cI + rw : cJ + (rw-16);
            bg[rw] = Jm2[(size_t)cidx*cap + i];
          }
          for (int p = 0; p < 32; ++p) {
            double s = 0.0;
            #pragma unroll 8
            for (int rw = 0; rw < 32; ++rw) s += bg[rw]*Vm[rw][p];
            int cidx = (p < 16) ? cI + p : cJ + (p-16);
            Jm2[(size_t)cidx*cap + i] = s;
          }
        }
      }
    }
    grid.sync();
  }
}

// ---------------- eigenvalues: lambda_k = J_k . G_k ----------------
__global__ void k_eig(char* ws) {
  const int* desc = (const int*)ws;
  double* eva = (double*)(ws + O_EVA);
  int* sid = (int*)(ws + O_SID);
  int wv = (blockIdx.x*blockDim.x + threadIdx.x) >> 6;
  int lane = threadIdx.x & 63;
  if (wv >= SORTN) return;
  if (wv >= NDIM) {
    if (lane == 0) { eva[wv] = 1e300; sid[wv] = wv; }
    return;
  }
  int g = 0;
  while (g < 8 && wv >= desc[16+g+1]) ++g;
  int k = wv - desc[16+g];
  int cap = (g < 8) ? CAPSM : CAP8;
  int ng = desc[g];
  size_t base = goffd(g) + (size_t)k*cap;
  const double* G = (const double*)(ws + O_G) + base;
  const double* J = (const double*)(ws + O_J) + base;
  double acc = 0.0;
  for (int i = lane; i < ng; i += 64) acc += J[i]*G[i];
  for (int s = 32; s > 0; s >>= 1) acc += __shfl_xor(acc, s, 64);
  if (lane == 0) { eva[wv] = acc; sid[wv] = wv; }
}

// ---------------- single-block bitonic sort ----------------
__global__ void k_sort(char* ws) {
  double* key = (double*)(ws + O_EVA);
  int* val = (int*)(ws + O_SID);
  int tid = threadIdx.x;
  for (int size = 2; size <= SORTN; size <<= 1) {
    for (int stride = size >> 1; stride > 0; stride >>= 1) {
      __syncthreads();
      for (int t = tid; t < SORTN/2; t += 1024) {
        int i = 2*t - (t & (stride-1));
        int j = i + stride;
        bool up = ((i & size) == 0);
        double ki = key[i], kj = key[j];
        if ((ki > kj) == up) {
          key[i] = kj; key[j] = ki;
          int v = val[i]; val[i] = val[j]; val[j] = v;
        }
      }
    }
  }
}

// ---------------- final: freq, ir, raman ----------------
__global__ void k_final(char* ws, float* __restrict__ out) {
  int m = blockIdx.x*256 + threadIdx.x;
  if (m >= NOUT) return;
  const int* desc = (const int*)ws;
  const double* eva = (const double*)(ws + O_EVA);
  const int* sid = (const int*)(ws + O_SID);
  int s = m + 6;
  double lam = eva[s];
  int gid = sid[s];
  int g = 0;
  while (g < 8 && gid >= desc[16+g+1]) ++g;
  int k = gid - desc[16+g];
  const double* R = (const double*)(ws + O_RB) + ((size_t)g*1152 + k)*9;
  double q0 = R[0], q1 = R[1], q2 = R[2];
  double ir = 42.2561*(q0*q0 + q1*q1 + q2*q2);
  double xx = R[3], xy = R[4], yy = R[5], xz = R[6], zy = R[7], zz = R[8];
  double alpha = (xx + yy + zz)/3.0;
  double gsq = 0.5*((xx-yy)*(xx-yy) + (yy-zz)*(yy-zz) + (zz-xx)*(zz-xx))
             + 3.0*(xy*xy + xz*xz + zy*zy);
  double raman = (45.0*alpha*alpha + 7.0*gsq)*0.078424;
  double freq = sqrt(fmax(lam, 0.0)*9.375829e28)/(2.0*PI_D)/2.9979245800e10*0.965;
  out[m] = (float)freq;
  out[NOUT + m] = (float)ir;
  out[2*NOUT + m] = (float)raman;
}

__global__ void k_fail(float* out) {
  int i = blockIdx.x*256 + threadIdx.x;
  if (i < 3*NOUT) out[i] = -7777.0f;
}

// ---------------- host ----------------
extern "C" void kernel_launch(void* const* d_in, const int* in_sizes, int n_in,
                              void* d_out, int out_size, void* d_ws, size_t ws_size,
                              hipStream_t stream) {
  const int* z = (const int*)d_in[1];
  const int* ei = (const int*)d_in[2];
  const float* Hi = (const float*)d_in[3];
  const float* Hij = (const float*)d_in[4];
  const float* ded = (const float*)d_in[5];
  const float* dep = (const float*)d_in[6];
  float* out = (float*)d_out;
  char* ws = (char*)d_ws;

  if (ws_size < WS_NEED) {
    k_fail<<<(3*NOUT+255)/256, 256, 0, stream>>>(out);
    return;
  }

  hipMemsetAsync(ws, 0, O_HCOL, stream);
  k_prep<<<1, 256, 0, stream>>>(z, ws);
  k_buildH<<<NA, 128, 0, stream>>>(ei, Hi, Hij, ws);
  k_coeff<<<1, 256, 0, stream>>>(ws);
  k_dt<<<(NDIM+255)/256, 256, 0, stream>>>(ded, dep, ws);

  float* TP = (float*)(ws + O_X1);
  float* TC = (float*)(ws + O_X1 + (size_t)NDIM*TLD*4);
  double* X1 = (double*)(ws + O_X1);
  double* X2 = (double*)(ws + O_X2);
  double* Sb = (double*)(ws + O_S);
  double* Pb = (double*)(ws + O_P);
  double* Zb = (double*)(ws + O_S);
  double* Dt = (double*)(ws + O_DT);

  for (int g = 0; g < NB; ++g) {
    int cap = capb(g);
    hipMemsetAsync((void*)(ws + O_Y), 0, (size_t)NDIM*YLD*4, stream);
    hipMemsetAsync((void*)TP, 0, (size_t)NDIM*TLD*4, stream);
    hipMemsetAsync((void*)TC, 0, (size_t)NDIM*TLD*4, stream);
    k_x0scatter<<<1, 1024, 0, stream>>>(ws, g, TC);
    {
      int ncb2 = (cap + 511)/512;
      for (int k = 1; k <= H_DEG[g]; ++k) {
        float* src = (k & 1) ? TC : TP;
        float* dst = (k & 1) ? TP : TC;
        k_cheb<<<dim3(NA/PGRP, ncb2), 256, 0, stream>>>(ws, g, k, src, dst, (k == 1) ? 1 : 0);
      }
    }
    k_upcast<<<(NDIM*YLD + 1023)/1024, 1024, 0, stream>>>(ws);
    // Newton-Schulz orthonormalization (5 iters), ping-pong X2 <-> X1
    double* Xa = X2; double* Xb = X1;
    dim3 gsq((cap+63)/64, (cap+63)/64);
    for (int it = 0; it < 5; ++it) {
      gemm_tn<<<gsq, 256, 0, stream>>>(Xa, Xa, Sb, cap, cap, NDIM, YLD, YLD, cap);
      gemm_nn<<<gsq, 256, 0, stream>>>(Sb, Sb, Pb, cap, cap, cap, cap, cap, cap);
      k_pbuild<<<((size_t)cap*cap + 255)/256, 256, 0, stream>>>(Pb, Sb, cap);
      gemm_nn<<<dim3((NDIM+63)/64, (cap+63)/64), 256, 0, stream>>>(Xa, Pb, Xb, NDIM, cap, cap, YLD, cap, YLD);
      double* tmp = Xa; Xa = Xb; Xb = tmp;
    }
    // PD_g = X^T Dt
    gemm_tn<<<dim3((cap+63)/64, 1), 256, 0, stream>>>(Xa, Dt,
        (double*)(ws + O_PD) + (size_t)g*1152*9, cap, 9, NDIM, YLD, 9, 9);
    // Heff_g = X^T (H X)  chunked
    double* Gg = (double*)(ws + O_G) + goffd(g);
    for (int zc = 0; zc < 2; ++zc) {
      int c0 = zc*ZCHW;
      int cwz = cap - c0; if (cwz > ZCHW) cwz = ZCHW;
      if (cwz <= 0) break;
      dim3 gz(NA, (cwz + 255)/256);
      k_spmm64<<<gz, 256, 0, stream>>>(ws, Xa + c0, Zb, cwz);
      gemm_tn<<<dim3((cap+63)/64, (cwz+63)/64), 256, 0, stream>>>(Xa, Zb, Gg + c0,
          cap, cwz, NDIM, YLD, ZCHW, cap);
    }
    k_jinit<<<((size_t)cap*cap + 255)/256, 256, 0, stream>>>((double*)(ws + O_J) + goffd(g), cap);
  }

  // joint block one-sided Jacobi on all bands
  {
    void* args[] = { (void*)&ws };
    hipLaunchCooperativeKernel((void*)k_bjac, dim3(TSLOTS), dim3(256), args, 0, stream);
  }

  k_eig<<<(SORTN*64)/256, 256, 0, stream>>>(ws);
  k_sort<<<1, 1024, 0, stream>>>(ws);

  for (int g = 0; g < NB; ++g) {
    int cap = capb(g);
    gemm_nn<<<dim3((cap+63)/64, 1), 256, 0, stream>>>(
        (double*)(ws + O_J) + goffd(g),
        (double*)(ws + O_PD) + (size_t)g*1152*9,
        (double*)(ws + O_RB) + (size_t)g*1152*9,
        cap, 9, cap, cap, 9, 9);
  }
  k_final<<<(NOUT+255)/256, 256, 0, stream>>>(ws, out);
}